// Round 4
// baseline (601.057 us; speedup 1.0000x reference)
//
#include <hip/hip_runtime.h>

// 2-layer GCN on MI355X.
// Strategy: build CSR-by-target once (histogram + single-block scan + fill),
// then gather-based aggregation (one wave per node, lane = feature) -> no f32 atomics.

__global__ __launch_bounds__(256) void init_kernel(float* deg, int* cnt, int N) {
  int i = blockIdx.x * 256 + threadIdx.x;
  if (i < N) { deg[i] = 1.0f; cnt[i] = 0; }  // deg starts at self-loop weight 1
}

__global__ __launch_bounds__(256) void deg_kernel(const int* __restrict__ col,
    const float* __restrict__ ew, float* deg, int* cnt, int E) {
  int e = blockIdx.x * 256 + threadIdx.x;
  if (e < E) {
    int c = col[e];
    atomicAdd(&deg[c], ew[e]);
    atomicAdd(&cnt[c], 1);
  }
}

__global__ __launch_bounds__(256) void rsqrt_kernel(float* deg, int N) {
  int i = blockIdx.x * 256 + threadIdx.x;
  if (i < N) {
    float d = deg[i];
    deg[i] = (d > 0.f) ? 1.0f / sqrtf(d) : 0.f;
  }
}

// Single-block exclusive scan of cnt[N] -> indptr[N+1]; zeroes cnt for reuse as cursor.
__global__ __launch_bounds__(1024) void scan_kernel(int* cnt, int* indptr, int N) {
  __shared__ int wsum[16];
  int tid = threadIdx.x;
  int lane = tid & 63, wid = tid >> 6;
  int carry = 0;
  for (int base = 0; base < N; base += 1024) {
    int i = base + tid;
    int v = (i < N) ? cnt[i] : 0;
    if (i < N) cnt[i] = 0;
    int x = v;
    #pragma unroll
    for (int d = 1; d < 64; d <<= 1) {
      int y = __shfl_up(x, d);
      if (lane >= d) x += y;
    }
    if (lane == 63) wsum[wid] = x;
    __syncthreads();
    if (wid == 0 && lane < 16) {
      int s = wsum[lane];
      #pragma unroll
      for (int d = 1; d < 16; d <<= 1) {
        int y = __shfl_up(s, d);
        if (lane >= d) s += y;
      }
      wsum[lane] = s;
    }
    __syncthreads();
    int waveoff = (wid == 0) ? 0 : wsum[wid - 1];
    if (i < N) indptr[i] = carry + waveoff + (x - v);
    int total = wsum[15];
    __syncthreads();            // protect wsum before next chunk overwrites
    carry += total;
  }
  if (tid == 0) indptr[N] = carry;
}

// Fill CSR: position via per-node cursor (int atomics only). Also computes norm.
__global__ __launch_bounds__(256) void fill_kernel(const int* __restrict__ row,
    const int* __restrict__ col, const float* __restrict__ ew,
    const float* __restrict__ dinv, const int* __restrict__ indptr,
    int* cnt, int* srow, float* snorm, int E) {
  int e = blockIdx.x * 256 + threadIdx.x;
  if (e < E) {
    int r = row[e], c = col[e];
    float nm = dinv[r] * ew[e] * dinv[c];
    int pos = indptr[c] + atomicAdd(&cnt[c], 1);
    srow[pos] = r;
    snorm[pos] = nm;
  }
}

// Y[N,64] = X[N,64] @ W[64,64]. One wave per 2 nodes, lane = output feature.
__global__ __launch_bounds__(256) void gemm64(const float* __restrict__ X,
    const float* __restrict__ W, float* __restrict__ Y, int N) {
  __shared__ float Ws[64 * 64];
  int tid = threadIdx.x;
  for (int i = tid; i < 64 * 64; i += 256) Ws[i] = W[i];
  __syncthreads();
  int lane = tid & 63;
  int wid = tid >> 6;
  int node = blockIdx.x * 8 + wid * 2;
  if (node >= N) return;                       // wave-uniform guard
  bool has1 = (node + 1 < N);
  float xa = X[(size_t)node * 64 + lane];
  float xb = has1 ? X[(size_t)(node + 1) * 64 + lane] : 0.f;
  float acc0 = 0.f, acc1 = 0.f;
  #pragma unroll
  for (int k = 0; k < 64; ++k) {
    float w = Ws[k * 64 + lane];               // stride 64: 2-way bank alias = free
    acc0 = fmaf(__shfl(xa, k), w, acc0);
    acc1 = fmaf(__shfl(xb, k), w, acc1);
  }
  Y[(size_t)node * 64 + lane] = acc0;
  if (has1) Y[(size_t)(node + 1) * 64 + lane] = acc1;
}

// out[c,:] = relu( dinv[c]^2*h1[c,:] + sum_e norm_e*h1[src_e,:] + b1 ). Wave per node.
// Dual accumulators: halve the fmaf dependency chain (gathers are independent).
__global__ __launch_bounds__(256) void agg64(const float* __restrict__ h1,
    const int* __restrict__ indptr, const int* __restrict__ srow,
    const float* __restrict__ snorm, const float* __restrict__ dinv,
    const float* __restrict__ b1, float* __restrict__ hout, int N) {
  int tid = threadIdx.x;
  int lane = tid & 63;
  int node = blockIdx.x * 4 + (tid >> 6);
  if (node >= N) return;                       // wave-uniform guard
  int s = indptr[node], eend = indptr[node + 1];
  float di = dinv[node];
  float acc = di * di * h1[(size_t)node * 64 + lane];
  float accB = 0.f;
  for (int base = s; base < eend; base += 64) {
    int m = min(64, eend - base);
    int rv = 0; float wv = 0.f;
    if (lane < m) { rv = srow[base + lane]; wv = snorm[base + lane]; }  // coalesced edge read
    int t = 0;
    for (; t + 1 < m; t += 2) {
      int r0 = __shfl(rv, t);     float w0 = __shfl(wv, t);
      int r1 = __shfl(rv, t + 1); float w1 = __shfl(wv, t + 1);
      acc  = fmaf(w0, h1[(size_t)r0 * 64 + lane], acc);   // 256B coalesced gather
      accB = fmaf(w1, h1[(size_t)r1 * 64 + lane], accB);
    }
    if (t < m) {
      int r = __shfl(rv, t); float w = __shfl(wv, t);
      acc = fmaf(w, h1[(size_t)r * 64 + lane], acc);
    }
  }
  acc += accB + b1[lane];
  hout[(size_t)node * 64 + lane] = fmaxf(acc, 0.f);
}

// Y[N,16] = Xh[N,64] @ W2[64,16]. 16 lanes per node (4 nodes per wave).
__global__ __launch_bounds__(256) void gemm16(const float* __restrict__ Xh,
    const float* __restrict__ W2, float* __restrict__ Y, int N) {
  __shared__ float Ws[64 * 16];
  int tid = threadIdx.x;
  for (int i = tid; i < 64 * 16; i += 256) Ws[i] = W2[i];
  __syncthreads();
  int lane = tid & 63;
  int sub = lane >> 4, j = lane & 15;
  int node = blockIdx.x * 16 + (tid >> 6) * 4 + sub;
  bool valid = node < N;
  float h0 = 0.f, h1v = 0.f, h2v = 0.f, h3v = 0.f;
  if (valid) {
    const float* x = Xh + (size_t)node * 64;
    h0 = x[j]; h1v = x[16 + j]; h2v = x[32 + j]; h3v = x[48 + j];
  }
  float acc = 0.f;
  #pragma unroll
  for (int t = 0; t < 16; ++t) {
    int sl = sub * 16 + t;
    acc = fmaf(__shfl(h0, sl),  Ws[t * 16 + j],        acc);
    acc = fmaf(__shfl(h1v, sl), Ws[(16 + t) * 16 + j], acc);
    acc = fmaf(__shfl(h2v, sl), Ws[(32 + t) * 16 + j], acc);
    acc = fmaf(__shfl(h3v, sl), Ws[(48 + t) * 16 + j], acc);
  }
  if (valid) Y[(size_t)node * 16 + j] = acc;
}

// out[c,:] = dinv^2*h2[c,:] + sum norm*h2[src,:] + b2. 16 lanes per node.
__global__ __launch_bounds__(256) void agg16(const float* __restrict__ h2,
    const int* __restrict__ indptr, const int* __restrict__ srow,
    const float* __restrict__ snorm, const float* __restrict__ dinv,
    const float* __restrict__ b2, float* __restrict__ out, int N) {
  int tid = threadIdx.x;
  int lane = tid & 63;
  int sub = lane >> 4, j = lane & 15;
  int node = blockIdx.x * 16 + (tid >> 6) * 4 + sub;
  bool valid = node < N;
  int s = 0, eend = 0;
  float acc = 0.f, accB = 0.f;
  if (valid) {
    s = indptr[node]; eend = indptr[node + 1];
    float di = dinv[node];
    acc = di * di * h2[(size_t)node * 16 + j];
  }
  for (int base = s; base < eend; base += 16) {
    int m = min(16, eend - base);
    int rv = 0; float wv = 0.f;
    if (j < m) { rv = srow[base + j]; wv = snorm[base + j]; }
    int t = 0;
    for (; t + 1 < m; t += 2) {
      int r0 = __shfl(rv, sub * 16 + t);     float w0 = __shfl(wv, sub * 16 + t);
      int r1 = __shfl(rv, sub * 16 + t + 1); float w1 = __shfl(wv, sub * 16 + t + 1);
      acc  = fmaf(w0, h2[(size_t)r0 * 16 + j], acc);
      accB = fmaf(w1, h2[(size_t)r1 * 16 + j], accB);
    }
    if (t < m) {
      int r = __shfl(rv, sub * 16 + t); float w = __shfl(wv, sub * 16 + t);
      acc = fmaf(w, h2[(size_t)r * 16 + j], acc);
    }
  }
  if (valid) out[(size_t)node * 16 + j] = acc + accB + b2[j];
}

extern "C" void kernel_launch(void* const* d_in, const int* in_sizes, int n_in,
                              void* d_out, int out_size, void* d_ws, size_t ws_size,
                              hipStream_t stream) {
  const float* X   = (const float*)d_in[0];
  const int*   eix = (const int*)d_in[1];   // int64 in ref demoted to int32 by JAX default
  const float* ew  = (const float*)d_in[2];
  const float* W1  = (const float*)d_in[3];
  const float* b1  = (const float*)d_in[4];
  const float* W2  = (const float*)d_in[5];
  const float* b2  = (const float*)d_in[6];
  float* out = (float*)d_out;

  const int N = in_sizes[0] / 64;
  const int E = in_sizes[1] / 2;
  const int* row = eix;
  const int* col = eix + E;

  char* ws = (char*)d_ws;
  size_t off = 0;
  auto alloc = [&](size_t bytes) -> void* {
    void* p = ws + off;
    off += (bytes + 255) & ~(size_t)255;
    return p;
  };
  float* dinv   = (float*)alloc((size_t)N * 4);
  int*   cnt    = (int*)  alloc((size_t)N * 4);
  int*   indptr = (int*)  alloc(((size_t)N + 1) * 4);
  int*   srow   = (int*)  alloc((size_t)E * 4);
  float* snorm  = (float*)alloc((size_t)E * 4);
  float* h1     = (float*)alloc((size_t)N * 64 * 4);
  float* hrelu  = (float*)alloc((size_t)N * 64 * 4);
  float* h2     = h1;   // h1 dead after agg64; reuse to shrink footprint
  if (off > ws_size) return;  // fail loudly: output stays poisoned

  int nbN = (N + 255) / 256;
  int nbE = (E + 255) / 256;

  init_kernel<<<nbN, 256, 0, stream>>>(dinv, cnt, N);
  deg_kernel<<<nbE, 256, 0, stream>>>(col, ew, dinv, cnt, E);
  rsqrt_kernel<<<nbN, 256, 0, stream>>>(dinv, N);
  scan_kernel<<<1, 1024, 0, stream>>>(cnt, indptr, N);
  fill_kernel<<<nbE, 256, 0, stream>>>(row, col, ew, dinv, indptr, cnt, srow, snorm, E);

  gemm64<<<(N + 7) / 8, 256, 0, stream>>>(X, W1, h1, N);
  agg64<<<(N + 3) / 4, 256, 0, stream>>>(h1, indptr, srow, snorm, dinv, b1, hrelu, N);
  gemm16<<<(N + 15) / 16, 256, 0, stream>>>(hrelu, W2, h2, N);
  agg16<<<(N + 15) / 16, 256, 0, stream>>>(h2, indptr, srow, snorm, dinv, b2, out, N);
}

// Round 6
// 461.115 us; speedup vs baseline: 1.3035x; 1.3035x over previous
//
#include <hip/hip_runtime.h>

// 2-layer GCN on MI355X. CSR-by-target built with ONE atomic per edge (rank trick),
// deg/dinv computed from CSR (no float atomics), gather-based aggregation.

struct __align__(8) Edge { int r; float w; };

__global__ __launch_bounds__(256) void zero_cnt(int* cnt, int N) {
  int i = blockIdx.x * 256 + threadIdx.x;
  if (i < N) cnt[i] = 0;
}

// rank[e] = arrival order of edge e at its target  (histogram + cursor in one atomic)
__global__ __launch_bounds__(256) void rank_kernel(const int* __restrict__ col,
    int* cnt, int* __restrict__ rank, int E) {
  int e = blockIdx.x * 256 + threadIdx.x;
  if (e < E) rank[e] = atomicAdd(&cnt[col[e]], 1);
}

// Single-block exclusive scan of cnt[N] -> indptr[N+1], 4 elems/thread.
__global__ __launch_bounds__(1024) void scan_kernel(const int* __restrict__ cnt,
    int* __restrict__ indptr, int N) {
  __shared__ int wsum[16];
  int tid = threadIdx.x;
  int lane = tid & 63, wid = tid >> 6;
  int carry = 0;
  for (int base = 0; base < N; base += 4096) {
    int i0 = base + tid * 4;
    int v0 = (i0 + 0 < N) ? cnt[i0 + 0] : 0;
    int v1 = (i0 + 1 < N) ? cnt[i0 + 1] : 0;
    int v2 = (i0 + 2 < N) ? cnt[i0 + 2] : 0;
    int v3 = (i0 + 3 < N) ? cnt[i0 + 3] : 0;
    int s = v0 + v1 + v2 + v3;
    int x = s;
    #pragma unroll
    for (int d = 1; d < 64; d <<= 1) { int y = __shfl_up(x, d); if (lane >= d) x += y; }
    if (lane == 63) wsum[wid] = x;
    __syncthreads();
    if (wid == 0 && lane < 16) {
      int t = wsum[lane];
      #pragma unroll
      for (int d = 1; d < 16; d <<= 1) { int y = __shfl_up(t, d); if (lane >= d) t += y; }
      wsum[lane] = t;
    }
    __syncthreads();
    int waveoff = (wid == 0) ? 0 : wsum[wid - 1];
    int b0 = carry + waveoff + (x - s);
    if (i0 + 0 < N) indptr[i0 + 0] = b0;
    if (i0 + 1 < N) indptr[i0 + 1] = b0 + v0;
    if (i0 + 2 < N) indptr[i0 + 2] = b0 + v0 + v1;
    if (i0 + 3 < N) indptr[i0 + 3] = b0 + v0 + v1 + v2;
    int total = wsum[15];
    __syncthreads();            // protect wsum before next chunk overwrites
    carry += total;
  }
  if (tid == 0) indptr[N] = carry;
}

// Deterministic placement: pos = indptr[col] + rank. NO atomics, one 8B scatter.
__global__ __launch_bounds__(256) void fill_kernel(const int* __restrict__ row,
    const int* __restrict__ col, const float* __restrict__ ew,
    const int* __restrict__ rank, const int* __restrict__ indptr,
    Edge* __restrict__ edges, int E) {
  int e = blockIdx.x * 256 + threadIdx.x;
  if (e < E) {
    int c = col[e];
    Edge ed; ed.r = row[e]; ed.w = ew[e];
    edges[indptr[c] + rank[e]] = ed;
  }
}

// dinv[c] = 1/sqrt(1 + sum of segment weights). 16 lanes per node, coalesced reads.
__global__ __launch_bounds__(256) void dinv_kernel(const Edge* __restrict__ edges,
    const int* __restrict__ indptr, float* __restrict__ dinv, int N) {
  int tid = threadIdx.x;
  int lane = tid & 63;
  int sub = lane >> 4, j = lane & 15;
  int node = blockIdx.x * 16 + (tid >> 6) * 4 + sub;
  bool valid = node < N;
  int s = 0, e = 0;
  if (valid) { s = indptr[node]; e = indptr[node + 1]; }
  float sum = 0.f;
  for (int b = s; b < e; b += 16) {
    int m = min(16, e - b);
    if (j < m) sum += edges[b + j].w;
  }
  #pragma unroll
  for (int d = 1; d < 16; d <<= 1) sum += __shfl_xor(sum, d, 16);
  if (valid && j == 0) dinv[node] = 1.0f / sqrtf(1.0f + sum);
}

// Pre-scale: w' = dinv[r] * ew   (sequential RW, small random gather of dinv)
__global__ __launch_bounds__(256) void norm_kernel(Edge* edges,
    const float* __restrict__ dinv, int E) {
  int i = blockIdx.x * 256 + threadIdx.x;
  if (i < E) {
    Edge e = edges[i];
    e.w *= dinv[e.r];
    edges[i] = e;
  }
}

// Y[N,64] = X[N,64] @ W[64,64]. One wave per 2 nodes, lane = output feature.
__global__ __launch_bounds__(256) void gemm64(const float* __restrict__ X,
    const float* __restrict__ W, float* __restrict__ Y, int N) {
  __shared__ float Ws[64 * 64];
  int tid = threadIdx.x;
  for (int i = tid; i < 64 * 64; i += 256) Ws[i] = W[i];
  __syncthreads();
  int lane = tid & 63;
  int wid = tid >> 6;
  int node = blockIdx.x * 8 + wid * 2;
  if (node >= N) return;                       // wave-uniform guard
  bool has1 = (node + 1 < N);
  float xa = X[(size_t)node * 64 + lane];
  float xb = has1 ? X[(size_t)(node + 1) * 64 + lane] : 0.f;
  float acc0 = 0.f, acc1 = 0.f;
  #pragma unroll
  for (int k = 0; k < 64; ++k) {
    float w = Ws[k * 64 + lane];               // stride 64: 2-way bank alias = free
    acc0 = fmaf(__shfl(xa, k), w, acc0);
    acc1 = fmaf(__shfl(xb, k), w, acc1);
  }
  Y[(size_t)node * 64 + lane] = acc0;
  if (has1) Y[(size_t)(node + 1) * 64 + lane] = acc1;
}

// out[c,:] = relu( di*( sum w'*h1[r] + di*h1[c] ) + b1 ). Wave per node, dual acc.
__global__ __launch_bounds__(256) void agg64(const float* __restrict__ h1,
    const int* __restrict__ indptr, const Edge* __restrict__ edges,
    const float* __restrict__ dinv, const float* __restrict__ b1,
    float* __restrict__ hout, int N) {
  int tid = threadIdx.x;
  int lane = tid & 63;
  int node = blockIdx.x * 4 + (tid >> 6);
  if (node >= N) return;                       // wave-uniform guard
  int s = indptr[node], eend = indptr[node + 1];
  float di = dinv[node];
  float self = di * h1[(size_t)node * 64 + lane];
  float acc = 0.f, accB = 0.f;
  for (int base = s; base < eend; base += 64) {
    int m = min(64, eend - base);
    int rv = 0; float wv = 0.f;
    if (lane < m) { Edge ed = edges[base + lane]; rv = ed.r; wv = ed.w; }  // 512B coalesced
    int t = 0;
    for (; t + 1 < m; t += 2) {
      int r0 = __shfl(rv, t);     float w0 = __shfl(wv, t);
      int r1 = __shfl(rv, t + 1); float w1 = __shfl(wv, t + 1);
      acc  = fmaf(w0, h1[(size_t)r0 * 64 + lane], acc);   // 256B coalesced gather
      accB = fmaf(w1, h1[(size_t)r1 * 64 + lane], accB);
    }
    if (t < m) {
      int r = __shfl(rv, t); float w = __shfl(wv, t);
      acc = fmaf(w, h1[(size_t)r * 64 + lane], acc);
    }
  }
  float res = fmaf(di, acc + accB + self, b1[lane]);
  hout[(size_t)node * 64 + lane] = fmaxf(res, 0.f);
}

// Y[N,16] = Xh[N,64] @ W2[64,16]. 16 lanes per node (4 nodes per wave).
__global__ __launch_bounds__(256) void gemm16(const float* __restrict__ Xh,
    const float* __restrict__ W2, float* __restrict__ Y, int N) {
  __shared__ float Ws[64 * 16];
  int tid = threadIdx.x;
  for (int i = tid; i < 64 * 16; i += 256) Ws[i] = W2[i];
  __syncthreads();
  int lane = tid & 63;
  int sub = lane >> 4, j = lane & 15;
  int node = blockIdx.x * 16 + (tid >> 6) * 4 + sub;
  bool valid = node < N;
  float h0 = 0.f, h1v = 0.f, h2v = 0.f, h3v = 0.f;
  if (valid) {
    const float* x = Xh + (size_t)node * 64;
    h0 = x[j]; h1v = x[16 + j]; h2v = x[32 + j]; h3v = x[48 + j];
  }
  float acc = 0.f;
  #pragma unroll
  for (int t = 0; t < 16; ++t) {
    int sl = sub * 16 + t;
    acc = fmaf(__shfl(h0, sl),  Ws[t * 16 + j],        acc);
    acc = fmaf(__shfl(h1v, sl), Ws[(16 + t) * 16 + j], acc);
    acc = fmaf(__shfl(h2v, sl), Ws[(32 + t) * 16 + j], acc);
    acc = fmaf(__shfl(h3v, sl), Ws[(48 + t) * 16 + j], acc);
  }
  if (valid) Y[(size_t)node * 16 + j] = acc;
}

// out[c,:] = di*( sum w'*h2[r] + di*h2[c] ) + b2. 16 lanes per node.
__global__ __launch_bounds__(256) void agg16(const float* __restrict__ h2,
    const int* __restrict__ indptr, const Edge* __restrict__ edges,
    const float* __restrict__ dinv, const float* __restrict__ b2,
    float* __restrict__ out, int N) {
  int tid = threadIdx.x;
  int lane = tid & 63;
  int sub = lane >> 4, j = lane & 15;
  int node = blockIdx.x * 16 + (tid >> 6) * 4 + sub;
  bool valid = node < N;
  int s = 0, eend = 0;
  float di = 0.f, self = 0.f;
  if (valid) {
    s = indptr[node]; eend = indptr[node + 1];
    di = dinv[node];
    self = di * h2[(size_t)node * 16 + j];
  }
  float acc = 0.f, accB = 0.f;
  for (int base = s; base < eend; base += 16) {
    int m = min(16, eend - base);
    int rv = 0; float wv = 0.f;
    if (j < m) { Edge ed = edges[base + j]; rv = ed.r; wv = ed.w; }
    int t = 0;
    for (; t + 1 < m; t += 2) {
      int r0 = __shfl(rv, sub * 16 + t);     float w0 = __shfl(wv, sub * 16 + t);
      int r1 = __shfl(rv, sub * 16 + t + 1); float w1 = __shfl(wv, sub * 16 + t + 1);
      acc  = fmaf(w0, h2[(size_t)r0 * 16 + j], acc);
      accB = fmaf(w1, h2[(size_t)r1 * 16 + j], accB);
    }
    if (t < m) {
      int r = __shfl(rv, sub * 16 + t); float w = __shfl(wv, sub * 16 + t);
      acc = fmaf(w, h2[(size_t)r * 16 + j], acc);
    }
  }
  if (valid) out[(size_t)node * 16 + j] = fmaf(di, acc + accB + self, b2[j]);
}

extern "C" void kernel_launch(void* const* d_in, const int* in_sizes, int n_in,
                              void* d_out, int out_size, void* d_ws, size_t ws_size,
                              hipStream_t stream) {
  const float* X   = (const float*)d_in[0];
  const int*   eix = (const int*)d_in[1];   // int32 on device (verified by passing bench)
  const float* ew  = (const float*)d_in[2];
  const float* W1  = (const float*)d_in[3];
  const float* b1  = (const float*)d_in[4];
  const float* W2  = (const float*)d_in[5];
  const float* b2  = (const float*)d_in[6];
  float* out = (float*)d_out;

  const int N = in_sizes[0] / 64;
  const int E = in_sizes[1] / 2;
  const int* row = eix;
  const int* col = eix + E;

  char* ws = (char*)d_ws;
  size_t off = 0;
  auto alloc = [&](size_t bytes) -> void* {
    void* p = ws + off;
    off += (bytes + 255) & ~(size_t)255;
    return p;
  };
  int*   cnt    = (int*)  alloc((size_t)N * 4);
  int*   indptr = (int*)  alloc(((size_t)N + 1) * 4);
  int*   rank   = (int*)  alloc((size_t)E * 4);
  Edge*  edges  = (Edge*) alloc((size_t)E * 8);
  float* dinv   = (float*)alloc((size_t)N * 4);
  float* h1     = (float*)alloc((size_t)N * 64 * 4);
  float* hrelu  = (float*)alloc((size_t)N * 64 * 4);
  float* h2     = h1;   // h1 dead after agg64; reuse
  if (off > ws_size) return;  // fail loudly: output stays poisoned

  int nbN = (N + 255) / 256;
  int nbE = (E + 255) / 256;

  zero_cnt   <<<nbN, 256, 0, stream>>>(cnt, N);
  rank_kernel<<<nbE, 256, 0, stream>>>(col, cnt, rank, E);
  scan_kernel<<<1, 1024, 0, stream>>>(cnt, indptr, N);
  fill_kernel<<<nbE, 256, 0, stream>>>(row, col, ew, rank, indptr, edges, E);
  dinv_kernel<<<(N + 15) / 16, 256, 0, stream>>>(edges, indptr, dinv, N);
  norm_kernel<<<nbE, 256, 0, stream>>>(edges, dinv, E);

  gemm64<<<(N + 7) / 8, 256, 0, stream>>>(X, W1, h1, N);
  agg64 <<<(N + 3) / 4, 256, 0, stream>>>(h1, indptr, edges, dinv, b1, hrelu, N);
  gemm16<<<(N + 15) / 16, 256, 0, stream>>>(hrelu, W2, h2, N);
  agg16 <<<(N + 15) / 16, 256, 0, stream>>>(h2, indptr, edges, dinv, b2, out, N);
}

// Round 8
// 380.231 us; speedup vs baseline: 1.5808x; 1.2127x over previous
//
#include <hip/hip_runtime.h>

// 2-layer GCN on MI355X. CSR-by-target via rank trick (1 atomic/edge),
// register-tiled VALU GEMMs (no fp32 MFMA on CDNA4), LDS-staged edge broadcast in agg.

struct __align__(8) Edge { int r; float w; };

#define XPAD 68   // 64+4: ng-groups land 16 dwords apart in banks -> <=2-way (free)

__global__ __launch_bounds__(256) void zero_cnt(int* cnt, int N) {
  int i = blockIdx.x * 256 + threadIdx.x;
  if (i < N) cnt[i] = 0;
}

// rank[e] = arrival order of edge e at its target (histogram + cursor in one atomic)
__global__ __launch_bounds__(256) void rank_kernel(const int* __restrict__ col,
    int* cnt, int* __restrict__ rank, int E) {
  int e = blockIdx.x * 256 + threadIdx.x;
  if (e < E) rank[e] = atomicAdd(&cnt[col[e]], 1);
}

// Single-block exclusive scan of cnt[N] -> indptr[N+1], 4 elems/thread.
__global__ __launch_bounds__(1024) void scan_kernel(const int* __restrict__ cnt,
    int* __restrict__ indptr, int N) {
  __shared__ int wsum[16];
  int tid = threadIdx.x;
  int lane = tid & 63, wid = tid >> 6;
  int carry = 0;
  for (int base = 0; base < N; base += 4096) {
    int i0 = base + tid * 4;
    int v0 = (i0 + 0 < N) ? cnt[i0 + 0] : 0;
    int v1 = (i0 + 1 < N) ? cnt[i0 + 1] : 0;
    int v2 = (i0 + 2 < N) ? cnt[i0 + 2] : 0;
    int v3 = (i0 + 3 < N) ? cnt[i0 + 3] : 0;
    int s = v0 + v1 + v2 + v3;
    int x = s;
    #pragma unroll
    for (int d = 1; d < 64; d <<= 1) { int y = __shfl_up(x, d); if (lane >= d) x += y; }
    if (lane == 63) wsum[wid] = x;
    __syncthreads();
    if (wid == 0 && lane < 16) {
      int t = wsum[lane];
      #pragma unroll
      for (int d = 1; d < 16; d <<= 1) { int y = __shfl_up(t, d); if (lane >= d) t += y; }
      wsum[lane] = t;
    }
    __syncthreads();
    int waveoff = (wid == 0) ? 0 : wsum[wid - 1];
    int b0 = carry + waveoff + (x - s);
    if (i0 + 0 < N) indptr[i0 + 0] = b0;
    if (i0 + 1 < N) indptr[i0 + 1] = b0 + v0;
    if (i0 + 2 < N) indptr[i0 + 2] = b0 + v0 + v1;
    if (i0 + 3 < N) indptr[i0 + 3] = b0 + v0 + v1 + v2;
    int total = wsum[15];
    __syncthreads();            // protect wsum before next chunk overwrites
    carry += total;
  }
  if (tid == 0) indptr[N] = carry;
}

// Deterministic placement: pos = indptr[col] + rank. NO atomics, one 8B scatter.
__global__ __launch_bounds__(256) void fill_kernel(const int* __restrict__ row,
    const int* __restrict__ col, const float* __restrict__ ew,
    const int* __restrict__ rank, const int* __restrict__ indptr,
    Edge* __restrict__ edges, int E) {
  int e = blockIdx.x * 256 + threadIdx.x;
  if (e < E) {
    int c = col[e];
    Edge ed; ed.r = row[e]; ed.w = ew[e];
    edges[indptr[c] + rank[e]] = ed;
  }
}

// dinv[c] = 1/sqrt(1 + sum of segment weights). 16 lanes per node, coalesced reads.
__global__ __launch_bounds__(256) void dinv_kernel(const Edge* __restrict__ edges,
    const int* __restrict__ indptr, float* __restrict__ dinv, int N) {
  int tid = threadIdx.x;
  int lane = tid & 63;
  int sub = lane >> 4, j = lane & 15;
  int node = blockIdx.x * 16 + (tid >> 6) * 4 + sub;
  bool valid = node < N;
  int s = 0, e = 0;
  if (valid) { s = indptr[node]; e = indptr[node + 1]; }
  float sum = 0.f;
  for (int b = s; b < e; b += 16) {
    int m = min(16, e - b);
    if (j < m) sum += edges[b + j].w;
  }
  #pragma unroll
  for (int d = 1; d < 16; d <<= 1) sum += __shfl_xor(sum, d, 16);
  if (valid && j == 0) dinv[node] = 1.0f / sqrtf(1.0f + sum);
}

// Pre-scale: w' = dinv[r] * ew   (sequential RW, small random gather of dinv)
__global__ __launch_bounds__(256) void norm_kernel(Edge* edges,
    const float* __restrict__ dinv, int E) {
  int i = blockIdx.x * 256 + threadIdx.x;
  if (i < E) {
    Edge e = edges[i];
    e.w *= dinv[e.r];
    edges[i] = e;
  }
}

// Y[N,64] = X[N,64] @ W[64,64]. Register-tiled: 64-node block, 4x4 per thread.
__global__ __launch_bounds__(256) void gemm64t(const float* __restrict__ X,
    const float* __restrict__ W, float* __restrict__ Y, int N) {
  __shared__ float Xs[64 * XPAD];
  __shared__ float Ws[64 * 64];
  int tid = threadIdx.x;
  int nb = blockIdx.x * 64;
  {
    const float4* Wv = (const float4*)W;      // 1024 float4
    float4* Wsv = (float4*)Ws;
    #pragma unroll
    for (int p = 0; p < 4; ++p) Wsv[p * 256 + tid] = Wv[p * 256 + tid];
  }
  #pragma unroll
  for (int p = 0; p < 4; ++p) {
    int g = p * 256 + tid;                    // float4 index in 64x64 tile
    int r = g >> 4, c4 = g & 15;
    int node = nb + r;
    float4 v = make_float4(0.f, 0.f, 0.f, 0.f);
    if (node < N) v = *(const float4*)&X[(size_t)node * 64 + c4 * 4];
    *(float4*)&Xs[r * XPAD + c4 * 4] = v;
  }
  __syncthreads();
  int jg = tid & 15;        // output cols jg*4..+3
  int ng = tid >> 4;        // nodes ng*4..+3
  float acc[4][4] = {};
  for (int k = 0; k < 64; k += 4) {
    float4 xv[4], wv[4];
    #pragma unroll
    for (int i = 0; i < 4; ++i) xv[i] = *(const float4*)&Xs[(ng * 4 + i) * XPAD + k];
    #pragma unroll
    for (int kk = 0; kk < 4; ++kk) wv[kk] = *(const float4*)&Ws[(k + kk) * 64 + jg * 4];
    #pragma unroll
    for (int i = 0; i < 4; ++i) {
      #pragma unroll
      for (int kk = 0; kk < 4; ++kk) {
        float xs = ((const float*)&xv[i])[kk];      // compile-time idx -> registers
        acc[i][0] = fmaf(xs, ((const float*)&wv[kk])[0], acc[i][0]);
        acc[i][1] = fmaf(xs, ((const float*)&wv[kk])[1], acc[i][1]);
        acc[i][2] = fmaf(xs, ((const float*)&wv[kk])[2], acc[i][2]);
        acc[i][3] = fmaf(xs, ((const float*)&wv[kk])[3], acc[i][3]);
      }
    }
  }
  #pragma unroll
  for (int i = 0; i < 4; ++i) {
    int node = nb + ng * 4 + i;
    if (node < N)
      *(float4*)&Y[(size_t)node * 64 + jg * 4] =
          make_float4(acc[i][0], acc[i][1], acc[i][2], acc[i][3]);
  }
}

// Y[N,16] = Xh[N,64] @ W2[64,16]. 64-node block, 1 node x 4 cols per thread.
__global__ __launch_bounds__(256) void gemm16t(const float* __restrict__ Xh,
    const float* __restrict__ W2, float* __restrict__ Y, int N) {
  __shared__ float Xs[64 * XPAD];
  __shared__ float Ws[64 * 16];
  int tid = threadIdx.x;
  int nb = blockIdx.x * 64;
  ((float4*)Ws)[tid] = ((const float4*)W2)[tid];  // 256 float4 exactly
  #pragma unroll
  for (int p = 0; p < 4; ++p) {
    int g = p * 256 + tid;
    int r = g >> 4, c4 = g & 15;
    int node = nb + r;
    float4 v = make_float4(0.f, 0.f, 0.f, 0.f);
    if (node < N) v = *(const float4*)&Xh[(size_t)node * 64 + c4 * 4];
    *(float4*)&Xs[r * XPAD + c4 * 4] = v;
  }
  __syncthreads();
  int node_l = tid >> 2;    // 0..63
  int jg = tid & 3;         // cols jg*4..+3
  float acc[4] = {};
  for (int k = 0; k < 64; k += 4) {
    float4 xv = *(const float4*)&Xs[node_l * XPAD + k];
    #pragma unroll
    for (int kk = 0; kk < 4; ++kk) {
      float4 wv = *(const float4*)&Ws[(k + kk) * 16 + jg * 4];
      float xs = ((const float*)&xv)[kk];
      acc[0] = fmaf(xs, wv.x, acc[0]);
      acc[1] = fmaf(xs, wv.y, acc[1]);
      acc[2] = fmaf(xs, wv.z, acc[2]);
      acc[3] = fmaf(xs, wv.w, acc[3]);
    }
  }
  int node = nb + node_l;
  if (node < N)
    *(float4*)&Y[(size_t)node * 16 + jg * 4] = make_float4(acc[0], acc[1], acc[2], acc[3]);
}

// out[c,:] = relu( di*( sum w'*h1[r] + di*h1[c] ) + b1 ). Wave per node.
// Edges staged in wave-private LDS; uniform ds_read_b64 broadcast (1 LDS op/edge).
__global__ __launch_bounds__(256) void agg64(const float* __restrict__ h1,
    const int* __restrict__ indptr, const Edge* __restrict__ edges,
    const float* __restrict__ dinv, const float* __restrict__ b1,
    float* __restrict__ hout, int N) {
  __shared__ Edge eds[4][64];
  int tid = threadIdx.x;
  int lane = tid & 63;
  int wid = tid >> 6;
  int node = blockIdx.x * 4 + wid;
  if (node >= N) return;                       // wave-uniform guard
  int s = indptr[node], eend = indptr[node + 1];
  float di = dinv[node];
  float self = di * h1[(size_t)node * 64 + lane];
  float acc = 0.f, accB = 0.f;
  for (int base = s; base < eend; base += 64) {
    int m = min(64, eend - base);
    if (lane < m) eds[wid][lane] = edges[base + lane];  // coalesced 512B + ds_write
    // wave-private region: compiler-inserted lgkmcnt ordering suffices, no barrier
    int t = 0;
    for (; t + 1 < m; t += 2) {
      Edge e0 = eds[wid][t];        // uniform addr -> broadcast, conflict-free
      Edge e1 = eds[wid][t + 1];
      acc  = fmaf(e0.w, h1[(size_t)e0.r * 64 + lane], acc);   // 256B coalesced gather
      accB = fmaf(e1.w, h1[(size_t)e1.r * 64 + lane], accB);
    }
    if (t < m) {
      Edge e0 = eds[wid][t];
      acc = fmaf(e0.w, h1[(size_t)e0.r * 64 + lane], acc);
    }
  }
  float res = fmaf(di, acc + accB + self, b1[lane]);
  hout[(size_t)node * 64 + lane] = fmaxf(res, 0.f);
}

// out[c,:] = di*( sum w'*h2[r] + di*h2[c] ) + b2. 16 lanes per node, LDS-staged edges.
__global__ __launch_bounds__(256) void agg16(const float* __restrict__ h2,
    const int* __restrict__ indptr, const Edge* __restrict__ edges,
    const float* __restrict__ dinv, const float* __restrict__ b2,
    float* __restrict__ out, int N) {
  __shared__ Edge eds[4][4][17];   // [wave][sub][edge], pad 17: subs 2 banks apart
  int tid = threadIdx.x;
  int lane = tid & 63;
  int wid = tid >> 6;
  int sub = lane >> 4, j = lane & 15;
  int node = blockIdx.x * 16 + wid * 4 + sub;
  bool valid = node < N;
  int s = 0, eend = 0;
  float di = 0.f, self = 0.f;
  if (valid) {
    s = indptr[node]; eend = indptr[node + 1];
    di = dinv[node];
    self = di * h2[(size_t)node * 16 + j];
  }
  float acc = 0.f, accB = 0.f;
  for (int base = s; base < eend; base += 16) {
    int m = min(16, eend - base);
    if (j < m) eds[wid][sub][j] = edges[base + j];
    int t = 0;
    for (; t + 1 < m; t += 2) {
      Edge e0 = eds[wid][sub][t];
      Edge e1 = eds[wid][sub][t + 1];
      acc  = fmaf(e0.w, h2[(size_t)e0.r * 16 + j], acc);
      accB = fmaf(e1.w, h2[(size_t)e1.r * 16 + j], accB);
    }
    if (t < m) {
      Edge e0 = eds[wid][sub][t];
      acc = fmaf(e0.w, h2[(size_t)e0.r * 16 + j], acc);
    }
  }
  if (valid) out[(size_t)node * 16 + j] = fmaf(di, acc + accB + self, b2[j]);
}

extern "C" void kernel_launch(void* const* d_in, const int* in_sizes, int n_in,
                              void* d_out, int out_size, void* d_ws, size_t ws_size,
                              hipStream_t stream) {
  const float* X   = (const float*)d_in[0];
  const int*   eix = (const int*)d_in[1];   // int32 on device (verified by passing bench)
  const float* ew  = (const float*)d_in[2];
  const float* W1  = (const float*)d_in[3];
  const float* b1  = (const float*)d_in[4];
  const float* W2  = (const float*)d_in[5];
  const float* b2  = (const float*)d_in[6];
  float* out = (float*)d_out;

  const int N = in_sizes[0] / 64;
  const int E = in_sizes[1] / 2;
  const int* row = eix;
  const int* col = eix + E;

  char* ws = (char*)d_ws;
  size_t off = 0;
  auto alloc = [&](size_t bytes) -> void* {
    void* p = ws + off;
    off += (bytes + 255) & ~(size_t)255;
    return p;
  };
  int*   cnt    = (int*)  alloc((size_t)N * 4);
  int*   indptr = (int*)  alloc(((size_t)N + 1) * 4);
  int*   rank   = (int*)  alloc((size_t)E * 4);
  Edge*  edges  = (Edge*) alloc((size_t)E * 8);
  float* dinv   = (float*)alloc((size_t)N * 4);
  float* h1     = (float*)alloc((size_t)N * 64 * 4);
  float* hrelu  = (float*)alloc((size_t)N * 64 * 4);
  float* h2     = h1;   // h1 dead after agg64; reuse
  if (off > ws_size) return;  // fail loudly: output stays poisoned

  int nbN = (N + 255) / 256;
  int nbE = (E + 255) / 256;
  int nbT = (N + 63) / 64;

  zero_cnt   <<<nbN, 256, 0, stream>>>(cnt, N);
  rank_kernel<<<nbE, 256, 0, stream>>>(col, cnt, rank, E);
  scan_kernel<<<1, 1024, 0, stream>>>(cnt, indptr, N);
  fill_kernel<<<nbE, 256, 0, stream>>>(row, col, ew, rank, indptr, edges, E);
  dinv_kernel<<<(N + 15) / 16, 256, 0, stream>>>(edges, indptr, dinv, N);
  norm_kernel<<<nbE, 256, 0, stream>>>(edges, dinv, E);

  gemm64t<<<nbT, 256, 0, stream>>>(X, W1, h1, N);
  agg64  <<<(N + 3) / 4, 256, 0, stream>>>(h1, indptr, edges, dinv, b1, hrelu, N);
  gemm16t<<<nbT, 256, 0, stream>>>(hrelu, W2, h2, N);
  agg16  <<<(N + 15) / 16, 256, 0, stream>>>(h2, indptr, edges, dinv, b2, out, N);
}